// Round 6
// baseline (174.456 us; speedup 1.0000x reference)
//
#include <hip/hip_runtime.h>
#include <cstdint>
#include <cstddef>

#define BB 512
#define NEn 100000
#define NRr 400
#define AA 256
#define ENTd 200
#define RELd 200
#define HISTd 400
#define ADIMd 400

__device__ __forceinline__ float dot4(const float4 a, const float4 b) {
  return a.x * b.x + a.y * b.y + a.z * b.z + a.w * b.w;
}
__device__ __forceinline__ float wave_rmax(float v) {
#pragma unroll
  for (int off = 32; off > 0; off >>= 1) v = fmaxf(v, __shfl_xor(v, off));
  return v;
}
__device__ __forceinline__ float wave_rsum(float v) {
#pragma unroll
  for (int off = 32; off > 0; off >>= 1) v += __shfl_xor(v, off);
  return v;
}

// ---------------------------------------------------------------------------
// prep1:
//  blk 0        : rel_sum -> ab = W5l.rel_sum + b5
//  blk 1..50    : RK = W4.rel + b4               [400,200]
//  blk 51..75   : P = 400 * W6a . W5r            [200,200]
//  blk 76..100  : W6bb = Watt_b . W6b            [200,200]
//  blk 101..296 : tiled transposes: relT[200][400], Watt_aT[400][200],
//                 W1T[800][400], W2T[400][400]
// ---------------------------------------------------------------------------
__global__ __launch_bounds__(256) void prep1_kernel(
    const float* __restrict__ rel_emb, const float* __restrict__ W4,
    const float* __restrict__ b4, const float* __restrict__ W5,
    const float* __restrict__ b5, const float* __restrict__ W6,
    const float* __restrict__ Watt, const float* __restrict__ W1,
    const float* __restrict__ W2, float* __restrict__ RK,
    float* __restrict__ P, float* __restrict__ W6bb, float* __restrict__ ab,
    float* __restrict__ relT, float* __restrict__ WaT,
    float* __restrict__ W1T, float* __restrict__ W2T) {
  int t = threadIdx.x;
  int blk = blockIdx.x;
  if (blk == 0) {
    __shared__ float rs[RELd];
    if (t < RELd) {
      float s = 0.f;
      for (int r = 0; r < NRr; r += 4) {
        s += rel_emb[(size_t)r * RELd + t] + rel_emb[(size_t)(r + 1) * RELd + t] +
             rel_emb[(size_t)(r + 2) * RELd + t] + rel_emb[(size_t)(r + 3) * RELd + t];
      }
      rs[t] = s;
    }
    __syncthreads();
    if (t < RELd) {
      float acc = b5[t];
      const float4* w = (const float4*)(W5 + (size_t)t * 400);
      const float4* rv = (const float4*)rs;
      for (int k = 0; k < 50; ++k) acc += dot4(w[k], rv[k]);
      ab[t] = acc;
    }
  } else if (blk <= 50) {
    int r0 = (blk - 1) * 8;
    __shared__ float re[8][RELd];
    for (int i = t; i < 8 * RELd; i += 256)
      re[i / RELd][i % RELd] = rel_emb[(size_t)(r0 + i / RELd) * RELd + i % RELd];
    __syncthreads();
    if (t < RELd) {
      float bv = b4[t];
      float acc[8];
#pragma unroll
      for (int s = 0; s < 8; ++s) acc[s] = bv;
      const float4* w = (const float4*)(W4 + (size_t)t * RELd);
      for (int k = 0; k < 50; ++k) {
        float4 wv = w[k];
#pragma unroll
        for (int s = 0; s < 8; ++s) acc[s] += dot4(wv, ((const float4*)re[s])[k]);
      }
#pragma unroll
      for (int s = 0; s < 8; ++s) RK[(size_t)(r0 + s) * RELd + t] = acc[s];
    }
  } else if (blk <= 75) {
    int i0 = (blk - 51) * 8;
    __shared__ float w6s[8][200];
    for (int i = t; i < 8 * 200; i += 256)
      w6s[i / 200][i % 200] = W6[(size_t)(i0 + i / 200) * 400 + i % 200];
    __syncthreads();
    if (t < 200) {
      int k = t;
      float acc[8] = {0, 0, 0, 0, 0, 0, 0, 0};
      for (int j = 0; j < 200; j += 4) {
        float r0v = W5[(size_t)j * 400 + 200 + k];
        float r1v = W5[(size_t)(j + 1) * 400 + 200 + k];
        float r2v = W5[(size_t)(j + 2) * 400 + 200 + k];
        float r3v = W5[(size_t)(j + 3) * 400 + 200 + k];
#pragma unroll
        for (int s = 0; s < 8; ++s)
          acc[s] += w6s[s][j] * r0v + w6s[s][j + 1] * r1v + w6s[s][j + 2] * r2v +
                    w6s[s][j + 3] * r3v;
      }
#pragma unroll
      for (int s = 0; s < 8; ++s) P[(size_t)(i0 + s) * 200 + k] = 400.f * acc[s];
    }
  } else if (blk <= 100) {
    int u0 = (blk - 76) * 8;
    __shared__ float wbs[8][200];
    for (int i = t; i < 8 * 200; i += 256)
      wbs[i / 200][i % 200] = Watt[(size_t)(u0 + i / 200) * 600 + 400 + i % 200];
    __syncthreads();
    if (t < 200) {
      int j = t;
      float acc[8] = {0, 0, 0, 0, 0, 0, 0, 0};
      for (int i = 0; i < 200; i += 4) {
        float r0v = W6[(size_t)i * 400 + 200 + j];
        float r1v = W6[(size_t)(i + 1) * 400 + 200 + j];
        float r2v = W6[(size_t)(i + 2) * 400 + 200 + j];
        float r3v = W6[(size_t)(i + 3) * 400 + 200 + j];
#pragma unroll
        for (int s = 0; s < 8; ++s)
          acc[s] += wbs[s][i] * r0v + wbs[s][i + 1] * r1v + wbs[s][i + 2] * r2v +
                    wbs[s][i + 3] * r3v;
      }
#pragma unroll
      for (int s = 0; s < 8; ++s) W6bb[(size_t)(u0 + s) * 200 + j] = acc[s];
    }
  } else {
    // tiled transpose: dst[j*M + i] = src[i*LD + j], i<M, j<N
    __shared__ float tlds[64][65];
    int tb = blk - 101;
    const float* src;
    float* dst;
    int M, N, LD, ti, tj;
    if (tb < 28) {
      src = rel_emb; dst = relT; M = 400; N = 200; LD = 200;
      ti = tb / 4; tj = tb % 4;
    } else if (tb < 56) {
      tb -= 28;
      src = Watt; dst = WaT; M = 200; N = 400; LD = 600;
      ti = tb / 7; tj = tb % 7;
    } else if (tb < 147) {
      tb -= 56;
      src = W1; dst = W1T; M = 400; N = 800; LD = 800;
      ti = tb / 13; tj = tb % 13;
    } else {
      tb -= 147;
      src = W2; dst = W2T; M = 400; N = 400; LD = 400;
      ti = tb / 7; tj = tb % 7;
    }
    int i0 = ti * 64, j0 = tj * 64;
    for (int idx = t; idx < 4096; idx += 256) {
      int r = idx >> 6, c = idx & 63;
      int i = i0 + r, j = j0 + c;
      if (i < M && j < N) tlds[r][c] = src[(size_t)i * LD + j];
    }
    __syncthreads();
    for (int idx = t; idx < 4096; idx += 256) {
      int r = idx >> 6, c = idx & 63;
      int j = j0 + r, i = i0 + c;
      if (i < M && j < N) dst[(size_t)j * M + i] = tlds[c][r];
    }
  }
}

// ---------------------------------------------------------------------------
// prep2:
//  blk 0..49   : S_T[k][r] = (W3^T.RK_r)[k] ; cvec_r = b3.RK_r
//  blk 50..74  : Q_T[k][j] = (Watt_b.P)[j][k]
//  blk 75..124 : REatt[r][j] = rel_r . W6bb_j       (row layout [400][200])
//  blk 125     : v1 = batt + Watt_b.(b6 + W6a.ab)
// ---------------------------------------------------------------------------
__global__ __launch_bounds__(256) void prep2_kernel(
    const float* __restrict__ rel_emb, const float* __restrict__ W3,
    const float* __restrict__ b3, const float* __restrict__ W6,
    const float* __restrict__ Watt, const float* __restrict__ batt,
    const float* __restrict__ b6, const float* __restrict__ RK,
    const float* __restrict__ P, const float* __restrict__ W6bb,
    const float* __restrict__ ab, float* __restrict__ S_T,
    float* __restrict__ cvec, float* __restrict__ Q_T,
    float* __restrict__ REatt, float* __restrict__ v1) {
  int t = threadIdx.x;
  int blk = blockIdx.x;
  if (blk < 50) {
    int r0 = blk * 8;
    __shared__ float rks[8][200];
    __shared__ float b3s[200];
    for (int i = t; i < 8 * 200; i += 256)
      rks[i / 200][i % 200] = RK[(size_t)(r0 + i / 200) * 200 + i % 200];
    if (t < 200) b3s[t] = b3[t];
    __syncthreads();
    if (t < 200) {
      int i = t;
      float acc[8] = {0, 0, 0, 0, 0, 0, 0, 0};
      for (int j = 0; j < 200; j += 4) {
        float w0 = W3[(size_t)j * 200 + i];
        float w1 = W3[(size_t)(j + 1) * 200 + i];
        float w2 = W3[(size_t)(j + 2) * 200 + i];
        float w3v = W3[(size_t)(j + 3) * 200 + i];
#pragma unroll
        for (int s = 0; s < 8; ++s)
          acc[s] += w0 * rks[s][j] + w1 * rks[s][j + 1] + w2 * rks[s][j + 2] +
                    w3v * rks[s][j + 3];
      }
      float4 s0 = make_float4(acc[0], acc[1], acc[2], acc[3]);
      float4 s1 = make_float4(acc[4], acc[5], acc[6], acc[7]);
      *(float4*)(S_T + (size_t)i * 400 + r0) = s0;
      *(float4*)(S_T + (size_t)i * 400 + r0 + 4) = s1;
    }
    {
      int w = t >> 6, lane = t & 63;
      float p0 = 0.f, p1 = 0.f;
      for (int j = lane; j < 200; j += 64) {
        p0 += b3s[j] * rks[w][j];
        p1 += b3s[j] * rks[w + 4][j];
      }
      p0 = wave_rsum(p0);
      p1 = wave_rsum(p1);
      if (lane == 0) {
        cvec[r0 + w] = p0;
        cvec[r0 + w + 4] = p1;
      }
    }
  } else if (blk < 75) {
    int u0 = (blk - 50) * 8;
    __shared__ float wbs[8][200];
    for (int i = t; i < 8 * 200; i += 256)
      wbs[i / 200][i % 200] = Watt[(size_t)(u0 + i / 200) * 600 + 400 + i % 200];
    __syncthreads();
    if (t < 200) {
      int k = t;
      float acc[8] = {0, 0, 0, 0, 0, 0, 0, 0};
      for (int i = 0; i < 200; i += 4) {
        float r0v = P[(size_t)i * 200 + k];
        float r1v = P[(size_t)(i + 1) * 200 + k];
        float r2v = P[(size_t)(i + 2) * 200 + k];
        float r3v = P[(size_t)(i + 3) * 200 + k];
#pragma unroll
        for (int s = 0; s < 8; ++s)
          acc[s] += wbs[s][i] * r0v + wbs[s][i + 1] * r1v + wbs[s][i + 2] * r2v +
                    wbs[s][i + 3] * r3v;
      }
      float4 s0 = make_float4(acc[0], acc[1], acc[2], acc[3]);
      float4 s1 = make_float4(acc[4], acc[5], acc[6], acc[7]);
      *(float4*)(Q_T + (size_t)k * 200 + u0) = s0;
      *(float4*)(Q_T + (size_t)k * 200 + u0 + 4) = s1;
    }
  } else if (blk < 125) {
    int r0 = (blk - 75) * 8;
    __shared__ float rels[8][200];
    for (int i = t; i < 8 * 200; i += 256)
      rels[i / 200][i % 200] = rel_emb[(size_t)(r0 + i / 200) * 200 + i % 200];
    __syncthreads();
    if (t < 200) {
      float acc[8] = {0, 0, 0, 0, 0, 0, 0, 0};
      const float4* w = (const float4*)(W6bb + (size_t)t * 200);
      for (int k = 0; k < 50; ++k) {
        float4 wv = w[k];
#pragma unroll
        for (int s = 0; s < 8; ++s) acc[s] += dot4(wv, ((const float4*)rels[s])[k]);
      }
#pragma unroll
      for (int s = 0; s < 8; ++s) REatt[(size_t)(r0 + s) * 200 + t] = acc[s];
    }
  } else {
    __shared__ float abs_[200];
    __shared__ float us[200];
    if (t < 200) abs_[t] = ab[t];
    __syncthreads();
    if (t < 200) {
      float u = b6[t];
      const float4* w = (const float4*)(W6 + (size_t)t * 400);
      const float4* rv = (const float4*)abs_;
      for (int k = 0; k < 50; ++k) u += dot4(w[k], rv[k]);
      us[t] = u;
    }
    __syncthreads();
    if (t < 200) {
      float v = batt[t];
      const float4* w = (const float4*)(Watt + (size_t)t * 600 + 400);
      const float4* rv = (const float4*)us;
      for (int k = 0; k < 50; ++k) v += dot4(w[k], rv[k]);
      v1[t] = v;
    }
  }
}

// ---------------------------------------------------------------------------
// x1: X = relu(W1T^T . cat(E,H,Q) + b1)  -- coalesced W1T[k][j] reads
// grid 128: 4 batch rows per block, 512 threads (400 compute lanes)
// ---------------------------------------------------------------------------
__global__ __launch_bounds__(512) void x1_kernel(
    const float* __restrict__ ent_emb, const float* __restrict__ rel_emb,
    const float* __restrict__ H, const int* __restrict__ e_idx,
    const int* __restrict__ q_idx, const float* __restrict__ W1T,
    const float* __restrict__ b1, float* __restrict__ X) {
  int b0 = blockIdx.x * 4;
  int t = threadIdx.x;
  __shared__ float cv[4][800];
  for (int i = t; i < 4 * 800; i += 512) {
    int s = i / 800, k = i % 800;
    float v;
    if (k < ENTd)
      v = ent_emb[(size_t)e_idx[b0 + s] * ENTd + k];
    else if (k < ENTd + HISTd)
      v = H[(size_t)(b0 + s) * HISTd + (k - ENTd)];
    else
      v = rel_emb[(size_t)q_idx[b0 + s] * RELd + (k - ENTd - HISTd)];
    cv[s][k] = v;
  }
  __syncthreads();
  if (t < 400) {
    int j = t;
    float bv = b1[j];
    float a0 = bv, a1 = bv, a2 = bv, a3 = bv;
    const float* wp = W1T + j;
    for (int k = 0; k < 800; k += 4) {
      float w0 = wp[k * 400], w1 = wp[(k + 1) * 400], w2 = wp[(k + 2) * 400],
            w3 = wp[(k + 3) * 400];
      a0 += w0 * cv[0][k] + w1 * cv[0][k + 1] + w2 * cv[0][k + 2] + w3 * cv[0][k + 3];
      a1 += w0 * cv[1][k] + w1 * cv[1][k + 1] + w2 * cv[1][k + 2] + w3 * cv[1][k + 3];
      a2 += w0 * cv[2][k] + w1 * cv[2][k + 1] + w2 * cv[2][k + 2] + w3 * cv[2][k + 3];
      a3 += w0 * cv[3][k] + w1 * cv[3][k + 1] + w2 * cv[3][k + 2] + w3 * cv[3][k + 3];
    }
    X[(size_t)(b0 + 0) * ADIMd + j] = fmaxf(a0, 0.f);
    X[(size_t)(b0 + 1) * ADIMd + j] = fmaxf(a1, 0.f);
    X[(size_t)(b0 + 2) * ADIMd + j] = fmaxf(a2, 0.f);
    X[(size_t)(b0 + 3) * ADIMd + j] = fmaxf(a3, 0.f);
  }
}

// ---------------------------------------------------------------------------
// x2: X2 = W2T^T . X + b2  -- coalesced; grid 128, 4 rows/block
// ---------------------------------------------------------------------------
__global__ __launch_bounds__(512) void x2_kernel(
    const float* __restrict__ X, const float* __restrict__ W2T,
    const float* __restrict__ b2, float* __restrict__ X2) {
  int b0 = blockIdx.x * 4;
  int t = threadIdx.x;
  __shared__ float cv[4][400];
  for (int i = t; i < 4 * 400; i += 512) cv[i / 400][i % 400] = X[(size_t)b0 * 400 + i];
  __syncthreads();
  if (t < 400) {
    int j = t;
    float bv = b2[j];
    float a0 = bv, a1 = bv, a2 = bv, a3 = bv;
    const float* wp = W2T + j;
    for (int k = 0; k < 400; k += 4) {
      float w0 = wp[k * 400], w1 = wp[(k + 1) * 400], w2 = wp[(k + 2) * 400],
            w3 = wp[(k + 3) * 400];
      a0 += w0 * cv[0][k] + w1 * cv[0][k + 1] + w2 * cv[0][k + 2] + w3 * cv[0][k + 3];
      a1 += w0 * cv[1][k] + w1 * cv[1][k + 1] + w2 * cv[1][k + 2] + w3 * cv[1][k + 3];
      a2 += w0 * cv[2][k] + w1 * cv[2][k + 1] + w2 * cv[2][k + 2] + w3 * cv[2][k + 3];
      a3 += w0 * cv[3][k] + w1 * cv[3][k + 1] + w2 * cv[3][k + 2] + w3 * cv[3][k + 3];
    }
    X2[(size_t)(b0 + 0) * ADIMd + j] = a0;
    X2[(size_t)(b0 + 1) * ADIMd + j] = a1;
    X2[(size_t)(b0 + 2) * ADIMd + j] = a2;
    X2[(size_t)(b0 + 3) * ADIMd + j] = a3;
  }
}

// ---------------------------------------------------------------------------
// tail: blk<128 -> fused_mid (4 batch rows); blk 128..639 -> scores (1 row).
// All dense reads coalesced via transposed layouts.
// ---------------------------------------------------------------------------
__global__ __launch_bounds__(512) void tail_kernel(
    const float* __restrict__ ent_emb, const float* __restrict__ rel_emb,
    const int* __restrict__ pred_id, const float* __restrict__ X2,
    const float* __restrict__ S_T, const float* __restrict__ cvec,
    const float* __restrict__ Q_T, const float* __restrict__ REatt,
    const float* __restrict__ relT, const float* __restrict__ WaT,
    const float* __restrict__ v1c, const int* __restrict__ r_space,
    const int* __restrict__ e_space, const float* __restrict__ mask,
    float* __restrict__ out_ratt, float* __restrict__ out_dist,
    float* __restrict__ out_ent) {
  int t = threadIdx.x;
  int w = t >> 6, lane = t & 63;
  // fused path shared
  __shared__ float pes[4][200];
  __shared__ float x2s[4][400];
  __shared__ float pp[4][400];
  __shared__ float av[4][200];
  __shared__ float attp[2][4][200];
  __shared__ float wred[4][2];
  // scores path shared
  __shared__ float x2sc[400];
  __shared__ float scl[256];
  __shared__ float wr4[4];

  if (blockIdx.x < 128) {
    int b0 = blockIdx.x * 4;
    for (int i = t; i < 800; i += 512)
      pes[i / 200][i % 200] = ent_emb[(size_t)pred_id[b0 + i / 200] * ENTd + i % 200];
    for (int i = t; i < 1600; i += 512)
      x2s[i / 400][i % 400] = X2[(size_t)b0 * 400 + i];
    __syncthreads();
    // --- la: thread r = t (coalesced S_T[k][r]) ---
    if (t < 400) {
      float c = cvec[t];
      float a0 = c, a1 = c, a2 = c, a3 = c;
      const float* sp = S_T + t;
      for (int k = 0; k < 200; k += 4) {
        float w0 = sp[k * 400], w1 = sp[(k + 1) * 400], w2 = sp[(k + 2) * 400],
              w3 = sp[(k + 3) * 400];
        a0 += w0 * pes[0][k] + w1 * pes[0][k + 1] + w2 * pes[0][k + 2] + w3 * pes[0][k + 3];
        a1 += w0 * pes[1][k] + w1 * pes[1][k + 1] + w2 * pes[1][k + 2] + w3 * pes[1][k + 3];
        a2 += w0 * pes[2][k] + w1 * pes[2][k + 1] + w2 * pes[2][k + 2] + w3 * pes[2][k + 3];
        a3 += w0 * pes[3][k] + w1 * pes[3][k + 1] + w2 * pes[3][k + 2] + w3 * pes[3][k + 3];
      }
      pp[0][t] = a0; pp[1][t] = a1; pp[2][t] = a2; pp[3][t] = a3;
    }
    __syncthreads();
    int row = w >> 1, half = w & 1;  // 2 waves per batch row
    // --- softmax(pp rows) ---
    {
      float m = -INFINITY;
      for (int r = half * 64 + lane; r < 400; r += 128) m = fmaxf(m, pp[row][r]);
      m = wave_rmax(m);
      if (lane == 0) wred[row][half] = m;
      __syncthreads();
      float gm = fmaxf(wred[row][0], wred[row][1]);
      __syncthreads();
      float sum = 0.f;
      for (int r = half * 64 + lane; r < 400; r += 128) {
        float e = expf(pp[row][r] - gm);
        pp[row][r] = e;
        sum += e;
      }
      sum = wave_rsum(sum);
      if (lane == 0) wred[row][half] = sum;
      __syncthreads();
      float inv = 1.f / (wred[row][0] + wred[row][1]);
      for (int r = half * 64 + lane; r < 400; r += 128) pp[row][r] *= inv;
    }
    __syncthreads();
    // --- attv: j = t%200, h = t/200; all reads coalesced ---
    if (t < 400) {
      int j = t % 200, h = t / 200;
      float b0a, b1a, b2a, b3a;
      if (h == 0) {
        float v = v1c[j];
        b0a = v; b1a = v; b2a = v; b3a = v;
      } else {
        b0a = 0.f; b1a = 0.f; b2a = 0.f; b3a = 0.f;
      }
      {  // Watt_a . x2 : k in [h*200, h*200+200)
        const float* wp = WaT + (size_t)(h * 200) * 200 + j;
        int kb = h * 200;
        for (int k = 0; k < 200; k += 4) {
          float w0 = wp[k * 200], w1 = wp[(k + 1) * 200], w2 = wp[(k + 2) * 200],
                w3 = wp[(k + 3) * 200];
          b0a += w0 * x2s[0][kb + k] + w1 * x2s[0][kb + k + 1] + w2 * x2s[0][kb + k + 2] + w3 * x2s[0][kb + k + 3];
          b1a += w0 * x2s[1][kb + k] + w1 * x2s[1][kb + k + 1] + w2 * x2s[1][kb + k + 2] + w3 * x2s[1][kb + k + 3];
          b2a += w0 * x2s[2][kb + k] + w1 * x2s[2][kb + k + 1] + w2 * x2s[2][kb + k + 2] + w3 * x2s[2][kb + k + 3];
          b3a += w0 * x2s[3][kb + k] + w1 * x2s[3][kb + k + 1] + w2 * x2s[3][kb + k + 2] + w3 * x2s[3][kb + k + 3];
        }
      }
      {  // Q . pe : k in [h*100, h*100+100)
        const float* qp = Q_T + (size_t)(h * 100) * 200 + j;
        int kb = h * 100;
        for (int k = 0; k < 100; k += 4) {
          float w0 = qp[k * 200], w1 = qp[(k + 1) * 200], w2 = qp[(k + 2) * 200],
                w3 = qp[(k + 3) * 200];
          b0a += w0 * pes[0][kb + k] + w1 * pes[0][kb + k + 1] + w2 * pes[0][kb + k + 2] + w3 * pes[0][kb + k + 3];
          b1a += w0 * pes[1][kb + k] + w1 * pes[1][kb + k + 1] + w2 * pes[1][kb + k + 2] + w3 * pes[1][kb + k + 3];
          b2a += w0 * pes[2][kb + k] + w1 * pes[2][kb + k + 1] + w2 * pes[2][kb + k + 2] + w3 * pes[2][kb + k + 3];
          b3a += w0 * pes[3][kb + k] + w1 * pes[3][kb + k + 1] + w2 * pes[3][kb + k + 2] + w3 * pes[3][kb + k + 3];
        }
      }
      {  // REatt^T . p : r in [h*200, h*200+200)
        const float* rp = REatt + (size_t)(h * 200) * 200 + j;
        int rb = h * 200;
        for (int r = 0; r < 200; r += 4) {
          float w0 = rp[r * 200], w1 = rp[(r + 1) * 200], w2 = rp[(r + 2) * 200],
                w3 = rp[(r + 3) * 200];
          b0a += w0 * pp[0][rb + r] + w1 * pp[0][rb + r + 1] + w2 * pp[0][rb + r + 2] + w3 * pp[0][rb + r + 3];
          b1a += w0 * pp[1][rb + r] + w1 * pp[1][rb + r + 1] + w2 * pp[1][rb + r + 2] + w3 * pp[1][rb + r + 3];
          b2a += w0 * pp[2][rb + r] + w1 * pp[2][rb + r + 1] + w2 * pp[2][rb + r + 2] + w3 * pp[2][rb + r + 3];
          b3a += w0 * pp[3][rb + r] + w1 * pp[3][rb + r + 1] + w2 * pp[3][rb + r + 2] + w3 * pp[3][rb + r + 3];
        }
      }
      attp[h][0][j] = b0a; attp[h][1][j] = b1a; attp[h][2][j] = b2a; attp[h][3][j] = b3a;
    }
    __syncthreads();
    if (t < 400) {
      int j = t % 200, s2 = t / 200;
      av[s2][j] = attp[0][s2][j] + attp[1][s2][j];
      av[s2 + 2][j] = attp[0][s2 + 2][j] + attp[1][s2 + 2][j];
    }
    __syncthreads();
    // --- logits: thread r = t (coalesced relT[k][r]) ---
    if (t < 400) {
      const float* rp = relT + t;
      float l0 = 0.f, l1 = 0.f, l2 = 0.f, l3 = 0.f;
      for (int k = 0; k < 200; k += 4) {
        float w0 = rp[k * 400], w1 = rp[(k + 1) * 400], w2 = rp[(k + 2) * 400],
              w3 = rp[(k + 3) * 400];
        l0 += w0 * av[0][k] + w1 * av[0][k + 1] + w2 * av[0][k + 2] + w3 * av[0][k + 3];
        l1 += w0 * av[1][k] + w1 * av[1][k + 1] + w2 * av[1][k + 2] + w3 * av[1][k + 3];
        l2 += w0 * av[2][k] + w1 * av[2][k + 1] + w2 * av[2][k + 2] + w3 * av[2][k + 3];
        l3 += w0 * av[3][k] + w1 * av[3][k + 1] + w2 * av[3][k + 2] + w3 * av[3][k + 3];
      }
      pp[0][t] = l0; pp[1][t] = l1; pp[2][t] = l2; pp[3][t] = l3;
    }
    __syncthreads();
    // --- softmax + write ratt ---
    {
      float m = -INFINITY;
      for (int r = half * 64 + lane; r < 400; r += 128) m = fmaxf(m, pp[row][r]);
      m = wave_rmax(m);
      if (lane == 0) wred[row][half] = m;
      __syncthreads();
      float gm = fmaxf(wred[row][0], wred[row][1]);
      __syncthreads();
      float sum = 0.f;
      for (int r = half * 64 + lane; r < 400; r += 128) {
        float e = expf(pp[row][r] - gm);
        pp[row][r] = e;
        sum += e;
      }
      sum = wave_rsum(sum);
      if (lane == 0) wred[row][half] = sum;
      __syncthreads();
      float inv = 1.f / (wred[row][0] + wred[row][1]);
      for (int r = half * 64 + lane; r < 400; r += 128)
        out_ratt[(size_t)(b0 + row) * 400 + r] = pp[row][r] * inv;
    }
  } else {
    // ---------------- scores: one batch row, wave-per-action ----------------
    int b = blockIdx.x - 128;
    if (t < 400) x2sc[t] = X2[(size_t)b * 400 + t];
    __syncthreads();
    const float4* x2f = (const float4*)x2sc;
    for (int a = w; a < 256; a += 8) {
      int r = r_space[(size_t)b * AA + a];
      int ei = e_space[(size_t)b * AA + a];
      float part = 0.f;
      if (lane < 50) {
        float4 rv = ((const float4*)(rel_emb + (size_t)r * RELd))[lane];
        float4 ev = ((const float4*)(ent_emb + (size_t)ei * ENTd))[lane];
        part = dot4(rv, x2f[lane]) + dot4(ev, x2f[50 + lane]);
      }
      float sc = wave_rsum(part);
      if (lane == 0)
        scl[a] = sc - (1.f - mask[(size_t)b * AA + a]) * 1e31f;
    }
    __syncthreads();
    float sc = (t < 256) ? scl[t] : -INFINITY;
    if (w < 4) {
      float m = wave_rmax(sc);
      if (lane == 0) wr4[w] = m;
    }
    __syncthreads();
    float gm = fmaxf(fmaxf(wr4[0], wr4[1]), fmaxf(wr4[2], wr4[3]));
    float e = (t < 256) ? expf(sc - gm) : 0.f;
    __syncthreads();
    if (w < 4) {
      float s2 = wave_rsum(e);
      if (lane == 0) wr4[w] = s2;
    }
    __syncthreads();
    float gs = wr4[0] + wr4[1] + wr4[2] + wr4[3];
    float p = e / gs;
    if (t < 256) out_dist[(size_t)b * AA + t] = p;
    float ent = (t < 256) ? -p * logf(p + 1e-20f) : 0.f;
    __syncthreads();
    if (w < 4) {
      float s3 = wave_rsum(ent);
      if (lane == 0) wr4[w] = s3;
    }
    __syncthreads();
    if (t == 0) out_ent[b] = wr4[0] + wr4[1] + wr4[2] + wr4[3];
  }
}

// ---------------------------------------------------------------------------
extern "C" void kernel_launch(void* const* d_in, const int* in_sizes, int n_in,
                              void* d_out, int out_size, void* d_ws,
                              size_t ws_size, hipStream_t stream) {
  const float* H = (const float*)d_in[0];
  const float* mask = (const float*)d_in[1];
  const float* ent_emb = (const float*)d_in[2];
  const float* rel_emb = (const float*)d_in[3];
  const float* W1 = (const float*)d_in[4];
  const float* b1 = (const float*)d_in[5];
  const float* W2 = (const float*)d_in[6];
  const float* b2 = (const float*)d_in[7];
  const float* W3 = (const float*)d_in[8];
  const float* b3 = (const float*)d_in[9];
  const float* W4 = (const float*)d_in[10];
  const float* b4 = (const float*)d_in[11];
  const float* W5 = (const float*)d_in[12];
  const float* b5 = (const float*)d_in[13];
  const float* W6 = (const float*)d_in[14];
  const float* b6 = (const float*)d_in[15];
  const float* Watt = (const float*)d_in[16];
  const float* batt = (const float*)d_in[17];
  const int* e_idx = (const int*)d_in[18];
  const int* q_idx = (const int*)d_in[19];
  const int* pred_id = (const int*)d_in[20];
  const int* r_space = (const int*)d_in[21];
  const int* e_space = (const int*)d_in[22];

  float* ws = (float*)d_ws;
  float* RK = ws;                   // 80000
  float* S_T = ws + 80000;          // 80000  [200][400]
  float* cvec = ws + 160000;        // 512
  float* P = ws + 160512;           // 40000
  float* Q_T = ws + 200512;         // 40000  [200][200]
  float* W6bb = ws + 240512;        // 40000
  float* REatt = ws + 280512;       // 80000  [400][200]
  float* relT = ws + 360512;        // 80000  [200][400]
  float* WaT = ws + 440512;         // 80000  [400][200]
  float* W1T = ws + 520512;         // 320000 [800][400]
  float* W2T = ws + 840512;         // 160000 [400][400]
  float* ab = ws + 1000512;         // 256
  float* v1 = ws + 1000768;         // 256
  float* X = ws + 1001024;          // 204800
  float* X2 = ws + 1205824;         // 204800  (end ~1.41M floats = 5.65 MB)

  float* out = (float*)d_out;
  float* out_dist = out;                 // [512,256]
  float* out_ent = out + BB * AA;        // [512]
  float* out_ratt = out + BB * AA + BB;  // [512,400]

  hipLaunchKernelGGL(prep1_kernel, dim3(297), dim3(256), 0, stream, rel_emb,
                     W4, b4, W5, b5, W6, Watt, W1, W2, RK, P, W6bb, ab, relT,
                     WaT, W1T, W2T);
  hipLaunchKernelGGL(prep2_kernel, dim3(126), dim3(256), 0, stream, rel_emb,
                     W3, b3, W6, Watt, batt, b6, RK, P, W6bb, ab, S_T, cvec,
                     Q_T, REatt, v1);
  hipLaunchKernelGGL(x1_kernel, dim3(128), dim3(512), 0, stream, ent_emb,
                     rel_emb, H, e_idx, q_idx, W1T, b1, X);
  hipLaunchKernelGGL(x2_kernel, dim3(128), dim3(512), 0, stream, X, W2T, b2,
                     X2);
  hipLaunchKernelGGL(tail_kernel, dim3(640), dim3(512), 0, stream, ent_emb,
                     rel_emb, pred_id, X2, S_T, cvec, Q_T, REatt, relT, WaT,
                     v1, r_space, e_space, mask, out_ratt, out_dist, out_ent);
}

// Round 7
// 160.257 us; speedup vs baseline: 1.0886x; 1.0886x over previous
//
#include <hip/hip_runtime.h>
#include <cstdint>
#include <cstddef>

#define BB 512
#define NEn 100000
#define NRr 400
#define AA 256
#define ENTd 200
#define RELd 200
#define HISTd 400
#define ADIMd 400

__device__ __forceinline__ float dot4(const float4 a, const float4 b) {
  return a.x * b.x + a.y * b.y + a.z * b.z + a.w * b.w;
}
__device__ __forceinline__ float wave_rmax(float v) {
#pragma unroll
  for (int off = 32; off > 0; off >>= 1) v = fmaxf(v, __shfl_xor(v, off));
  return v;
}
__device__ __forceinline__ float wave_rsum(float v) {
#pragma unroll
  for (int off = 32; off > 0; off >>= 1) v += __shfl_xor(v, off);
  return v;
}

// ---------------------------------------------------------------------------
// prep1 (unchanged): RK, P, W6bb, ab + tiled transposes relT/WaT/W1T/W2T
// ---------------------------------------------------------------------------
__global__ __launch_bounds__(256) void prep1_kernel(
    const float* __restrict__ rel_emb, const float* __restrict__ W4,
    const float* __restrict__ b4, const float* __restrict__ W5,
    const float* __restrict__ b5, const float* __restrict__ W6,
    const float* __restrict__ Watt, const float* __restrict__ W1,
    const float* __restrict__ W2, float* __restrict__ RK,
    float* __restrict__ P, float* __restrict__ W6bb, float* __restrict__ ab,
    float* __restrict__ relT, float* __restrict__ WaT,
    float* __restrict__ W1T, float* __restrict__ W2T) {
  int t = threadIdx.x;
  int blk = blockIdx.x;
  if (blk == 0) {
    __shared__ float rs[RELd];
    if (t < RELd) {
      float s = 0.f;
      for (int r = 0; r < NRr; r += 4) {
        s += rel_emb[(size_t)r * RELd + t] + rel_emb[(size_t)(r + 1) * RELd + t] +
             rel_emb[(size_t)(r + 2) * RELd + t] + rel_emb[(size_t)(r + 3) * RELd + t];
      }
      rs[t] = s;
    }
    __syncthreads();
    if (t < RELd) {
      float acc = b5[t];
      const float4* w = (const float4*)(W5 + (size_t)t * 400);
      const float4* rv = (const float4*)rs;
      for (int k = 0; k < 50; ++k) acc += dot4(w[k], rv[k]);
      ab[t] = acc;
    }
  } else if (blk <= 50) {
    int r0 = (blk - 1) * 8;
    __shared__ float re[8][RELd];
    for (int i = t; i < 8 * RELd; i += 256)
      re[i / RELd][i % RELd] = rel_emb[(size_t)(r0 + i / RELd) * RELd + i % RELd];
    __syncthreads();
    if (t < RELd) {
      float bv = b4[t];
      float acc[8];
#pragma unroll
      for (int s = 0; s < 8; ++s) acc[s] = bv;
      const float4* w = (const float4*)(W4 + (size_t)t * RELd);
      for (int k = 0; k < 50; ++k) {
        float4 wv = w[k];
#pragma unroll
        for (int s = 0; s < 8; ++s) acc[s] += dot4(wv, ((const float4*)re[s])[k]);
      }
#pragma unroll
      for (int s = 0; s < 8; ++s) RK[(size_t)(r0 + s) * RELd + t] = acc[s];
    }
  } else if (blk <= 75) {
    int i0 = (blk - 51) * 8;
    __shared__ float w6s[8][200];
    for (int i = t; i < 8 * 200; i += 256)
      w6s[i / 200][i % 200] = W6[(size_t)(i0 + i / 200) * 400 + i % 200];
    __syncthreads();
    if (t < 200) {
      int k = t;
      float acc[8] = {0, 0, 0, 0, 0, 0, 0, 0};
      for (int j = 0; j < 200; j += 4) {
        float r0v = W5[(size_t)j * 400 + 200 + k];
        float r1v = W5[(size_t)(j + 1) * 400 + 200 + k];
        float r2v = W5[(size_t)(j + 2) * 400 + 200 + k];
        float r3v = W5[(size_t)(j + 3) * 400 + 200 + k];
#pragma unroll
        for (int s = 0; s < 8; ++s)
          acc[s] += w6s[s][j] * r0v + w6s[s][j + 1] * r1v + w6s[s][j + 2] * r2v +
                    w6s[s][j + 3] * r3v;
      }
#pragma unroll
      for (int s = 0; s < 8; ++s) P[(size_t)(i0 + s) * 200 + k] = 400.f * acc[s];
    }
  } else if (blk <= 100) {
    int u0 = (blk - 76) * 8;
    __shared__ float wbs[8][200];
    for (int i = t; i < 8 * 200; i += 256)
      wbs[i / 200][i % 200] = Watt[(size_t)(u0 + i / 200) * 600 + 400 + i % 200];
    __syncthreads();
    if (t < 200) {
      int j = t;
      float acc[8] = {0, 0, 0, 0, 0, 0, 0, 0};
      for (int i = 0; i < 200; i += 4) {
        float r0v = W6[(size_t)i * 400 + 200 + j];
        float r1v = W6[(size_t)(i + 1) * 400 + 200 + j];
        float r2v = W6[(size_t)(i + 2) * 400 + 200 + j];
        float r3v = W6[(size_t)(i + 3) * 400 + 200 + j];
#pragma unroll
        for (int s = 0; s < 8; ++s)
          acc[s] += wbs[s][i] * r0v + wbs[s][i + 1] * r1v + wbs[s][i + 2] * r2v +
                    wbs[s][i + 3] * r3v;
      }
#pragma unroll
      for (int s = 0; s < 8; ++s) W6bb[(size_t)(u0 + s) * 200 + j] = acc[s];
    }
  } else {
    __shared__ float tlds[64][65];
    int tb = blk - 101;
    const float* src;
    float* dst;
    int M, N, LD, ti, tj;
    if (tb < 28) {
      src = rel_emb; dst = relT; M = 400; N = 200; LD = 200;
      ti = tb / 4; tj = tb % 4;
    } else if (tb < 56) {
      tb -= 28;
      src = Watt; dst = WaT; M = 200; N = 400; LD = 600;
      ti = tb / 7; tj = tb % 7;
    } else if (tb < 147) {
      tb -= 56;
      src = W1; dst = W1T; M = 400; N = 800; LD = 800;
      ti = tb / 13; tj = tb % 13;
    } else {
      tb -= 147;
      src = W2; dst = W2T; M = 400; N = 400; LD = 400;
      ti = tb / 7; tj = tb % 7;
    }
    int i0 = ti * 64, j0 = tj * 64;
    for (int idx = t; idx < 4096; idx += 256) {
      int r = idx >> 6, c = idx & 63;
      int i = i0 + r, j = j0 + c;
      if (i < M && j < N) tlds[r][c] = src[(size_t)i * LD + j];
    }
    __syncthreads();
    for (int idx = t; idx < 4096; idx += 256) {
      int r = idx >> 6, c = idx & 63;
      int j = j0 + r, i = i0 + c;
      if (i < M && j < N) dst[(size_t)j * M + i] = tlds[c][r];
    }
  }
}

// ---------------------------------------------------------------------------
// prep2 (unchanged): S_T, cvec, Q_T, REatt, v1
// ---------------------------------------------------------------------------
__global__ __launch_bounds__(256) void prep2_kernel(
    const float* __restrict__ rel_emb, const float* __restrict__ W3,
    const float* __restrict__ b3, const float* __restrict__ W6,
    const float* __restrict__ Watt, const float* __restrict__ batt,
    const float* __restrict__ b6, const float* __restrict__ RK,
    const float* __restrict__ P, const float* __restrict__ W6bb,
    const float* __restrict__ ab, float* __restrict__ S_T,
    float* __restrict__ cvec, float* __restrict__ Q_T,
    float* __restrict__ REatt, float* __restrict__ v1) {
  int t = threadIdx.x;
  int blk = blockIdx.x;
  if (blk < 50) {
    int r0 = blk * 8;
    __shared__ float rks[8][200];
    __shared__ float b3s[200];
    for (int i = t; i < 8 * 200; i += 256)
      rks[i / 200][i % 200] = RK[(size_t)(r0 + i / 200) * 200 + i % 200];
    if (t < 200) b3s[t] = b3[t];
    __syncthreads();
    if (t < 200) {
      int i = t;
      float acc[8] = {0, 0, 0, 0, 0, 0, 0, 0};
      for (int j = 0; j < 200; j += 4) {
        float w0 = W3[(size_t)j * 200 + i];
        float w1 = W3[(size_t)(j + 1) * 200 + i];
        float w2 = W3[(size_t)(j + 2) * 200 + i];
        float w3v = W3[(size_t)(j + 3) * 200 + i];
#pragma unroll
        for (int s = 0; s < 8; ++s)
          acc[s] += w0 * rks[s][j] + w1 * rks[s][j + 1] + w2 * rks[s][j + 2] +
                    w3v * rks[s][j + 3];
      }
      float4 s0 = make_float4(acc[0], acc[1], acc[2], acc[3]);
      float4 s1 = make_float4(acc[4], acc[5], acc[6], acc[7]);
      *(float4*)(S_T + (size_t)i * 400 + r0) = s0;
      *(float4*)(S_T + (size_t)i * 400 + r0 + 4) = s1;
    }
    {
      int w = t >> 6, lane = t & 63;
      float p0 = 0.f, p1 = 0.f;
      for (int j = lane; j < 200; j += 64) {
        p0 += b3s[j] * rks[w][j];
        p1 += b3s[j] * rks[w + 4][j];
      }
      p0 = wave_rsum(p0);
      p1 = wave_rsum(p1);
      if (lane == 0) {
        cvec[r0 + w] = p0;
        cvec[r0 + w + 4] = p1;
      }
    }
  } else if (blk < 75) {
    int u0 = (blk - 50) * 8;
    __shared__ float wbs[8][200];
    for (int i = t; i < 8 * 200; i += 256)
      wbs[i / 200][i % 200] = Watt[(size_t)(u0 + i / 200) * 600 + 400 + i % 200];
    __syncthreads();
    if (t < 200) {
      int k = t;
      float acc[8] = {0, 0, 0, 0, 0, 0, 0, 0};
      for (int i = 0; i < 200; i += 4) {
        float r0v = P[(size_t)i * 200 + k];
        float r1v = P[(size_t)(i + 1) * 200 + k];
        float r2v = P[(size_t)(i + 2) * 200 + k];
        float r3v = P[(size_t)(i + 3) * 200 + k];
#pragma unroll
        for (int s = 0; s < 8; ++s)
          acc[s] += wbs[s][i] * r0v + wbs[s][i + 1] * r1v + wbs[s][i + 2] * r2v +
                    wbs[s][i + 3] * r3v;
      }
      float4 s0 = make_float4(acc[0], acc[1], acc[2], acc[3]);
      float4 s1 = make_float4(acc[4], acc[5], acc[6], acc[7]);
      *(float4*)(Q_T + (size_t)k * 200 + u0) = s0;
      *(float4*)(Q_T + (size_t)k * 200 + u0 + 4) = s1;
    }
  } else if (blk < 125) {
    int r0 = (blk - 75) * 8;
    __shared__ float rels[8][200];
    for (int i = t; i < 8 * 200; i += 256)
      rels[i / 200][i % 200] = rel_emb[(size_t)(r0 + i / 200) * 200 + i % 200];
    __syncthreads();
    if (t < 200) {
      float acc[8] = {0, 0, 0, 0, 0, 0, 0, 0};
      const float4* w = (const float4*)(W6bb + (size_t)t * 200);
      for (int k = 0; k < 50; ++k) {
        float4 wv = w[k];
#pragma unroll
        for (int s = 0; s < 8; ++s) acc[s] += dot4(wv, ((const float4*)rels[s])[k]);
      }
#pragma unroll
      for (int s = 0; s < 8; ++s) REatt[(size_t)(r0 + s) * 200 + t] = acc[s];
    }
  } else {
    __shared__ float abs_[200];
    __shared__ float us[200];
    if (t < 200) abs_[t] = ab[t];
    __syncthreads();
    if (t < 200) {
      float u = b6[t];
      const float4* w = (const float4*)(W6 + (size_t)t * 400);
      const float4* rv = (const float4*)abs_;
      for (int k = 0; k < 50; ++k) u += dot4(w[k], rv[k]);
      us[t] = u;
    }
    __syncthreads();
    if (t < 200) {
      float v = batt[t];
      const float4* w = (const float4*)(Watt + (size_t)t * 600 + 400);
      const float4* rv = (const float4*)us;
      for (int k = 0; k < 50; ++k) v += dot4(w[k], rv[k]);
      v1[t] = v;
    }
  }
}

// ---------------------------------------------------------------------------
// x1: X = relu(W1T^T . cat(E,H,Q) + b1)  (unchanged)
// ---------------------------------------------------------------------------
__global__ __launch_bounds__(512) void x1_kernel(
    const float* __restrict__ ent_emb, const float* __restrict__ rel_emb,
    const float* __restrict__ H, const int* __restrict__ e_idx,
    const int* __restrict__ q_idx, const float* __restrict__ W1T,
    const float* __restrict__ b1, float* __restrict__ X) {
  int b0 = blockIdx.x * 4;
  int t = threadIdx.x;
  __shared__ float cv[4][800];
  for (int i = t; i < 4 * 800; i += 512) {
    int s = i / 800, k = i % 800;
    float v;
    if (k < ENTd)
      v = ent_emb[(size_t)e_idx[b0 + s] * ENTd + k];
    else if (k < ENTd + HISTd)
      v = H[(size_t)(b0 + s) * HISTd + (k - ENTd)];
    else
      v = rel_emb[(size_t)q_idx[b0 + s] * RELd + (k - ENTd - HISTd)];
    cv[s][k] = v;
  }
  __syncthreads();
  if (t < 400) {
    int j = t;
    float bv = b1[j];
    float a0 = bv, a1 = bv, a2 = bv, a3 = bv;
    const float* wp = W1T + j;
    for (int k = 0; k < 800; k += 4) {
      float w0 = wp[k * 400], w1 = wp[(k + 1) * 400], w2 = wp[(k + 2) * 400],
            w3 = wp[(k + 3) * 400];
      a0 += w0 * cv[0][k] + w1 * cv[0][k + 1] + w2 * cv[0][k + 2] + w3 * cv[0][k + 3];
      a1 += w0 * cv[1][k] + w1 * cv[1][k + 1] + w2 * cv[1][k + 2] + w3 * cv[1][k + 3];
      a2 += w0 * cv[2][k] + w1 * cv[2][k + 1] + w2 * cv[2][k + 2] + w3 * cv[2][k + 3];
      a3 += w0 * cv[3][k] + w1 * cv[3][k + 1] + w2 * cv[3][k + 2] + w3 * cv[3][k + 3];
    }
    X[(size_t)(b0 + 0) * ADIMd + j] = fmaxf(a0, 0.f);
    X[(size_t)(b0 + 1) * ADIMd + j] = fmaxf(a1, 0.f);
    X[(size_t)(b0 + 2) * ADIMd + j] = fmaxf(a2, 0.f);
    X[(size_t)(b0 + 3) * ADIMd + j] = fmaxf(a3, 0.f);
  }
}

// ---------------------------------------------------------------------------
// x2rx: X2 = W2T^T . X + b2 ; then RX[b][r] = rel_emb[r] . X2[b][:200]
// grid 128, 4 rows/block
// ---------------------------------------------------------------------------
__global__ __launch_bounds__(512) void x2rx_kernel(
    const float* __restrict__ X, const float* __restrict__ W2T,
    const float* __restrict__ b2, const float* __restrict__ relT,
    float* __restrict__ X2, float* __restrict__ RX) {
  int b0 = blockIdx.x * 4;
  int t = threadIdx.x;
  __shared__ float cv[4][400];
  __shared__ float x2lo[4][200];
  for (int i = t; i < 4 * 400; i += 512) cv[i / 400][i % 400] = X[(size_t)b0 * 400 + i];
  __syncthreads();
  if (t < 400) {
    int j = t;
    float bv = b2[j];
    float a0 = bv, a1 = bv, a2 = bv, a3 = bv;
    const float* wp = W2T + j;
    for (int k = 0; k < 400; k += 4) {
      float w0 = wp[k * 400], w1 = wp[(k + 1) * 400], w2 = wp[(k + 2) * 400],
            w3 = wp[(k + 3) * 400];
      a0 += w0 * cv[0][k] + w1 * cv[0][k + 1] + w2 * cv[0][k + 2] + w3 * cv[0][k + 3];
      a1 += w0 * cv[1][k] + w1 * cv[1][k + 1] + w2 * cv[1][k + 2] + w3 * cv[1][k + 3];
      a2 += w0 * cv[2][k] + w1 * cv[2][k + 1] + w2 * cv[2][k + 2] + w3 * cv[2][k + 3];
      a3 += w0 * cv[3][k] + w1 * cv[3][k + 1] + w2 * cv[3][k + 2] + w3 * cv[3][k + 3];
    }
    X2[(size_t)(b0 + 0) * ADIMd + j] = a0;
    X2[(size_t)(b0 + 1) * ADIMd + j] = a1;
    X2[(size_t)(b0 + 2) * ADIMd + j] = a2;
    X2[(size_t)(b0 + 3) * ADIMd + j] = a3;
    if (j < 200) {
      x2lo[0][j] = a0; x2lo[1][j] = a1; x2lo[2][j] = a2; x2lo[3][j] = a3;
    }
  }
  __syncthreads();
  if (t < 400) {
    int r = t;
    const float* rp = relT + r;
    float a0 = 0.f, a1 = 0.f, a2 = 0.f, a3 = 0.f;
    for (int k = 0; k < 200; k += 4) {
      float w0 = rp[k * 400], w1 = rp[(k + 1) * 400], w2 = rp[(k + 2) * 400],
            w3 = rp[(k + 3) * 400];
      a0 += w0 * x2lo[0][k] + w1 * x2lo[0][k + 1] + w2 * x2lo[0][k + 2] + w3 * x2lo[0][k + 3];
      a1 += w0 * x2lo[1][k] + w1 * x2lo[1][k + 1] + w2 * x2lo[1][k + 2] + w3 * x2lo[1][k + 3];
      a2 += w0 * x2lo[2][k] + w1 * x2lo[2][k + 1] + w2 * x2lo[2][k + 2] + w3 * x2lo[2][k + 3];
      a3 += w0 * x2lo[3][k] + w1 * x2lo[3][k + 1] + w2 * x2lo[3][k + 2] + w3 * x2lo[3][k + 3];
    }
    RX[(size_t)(b0 + 0) * NRr + r] = a0;
    RX[(size_t)(b0 + 1) * NRr + r] = a1;
    RX[(size_t)(b0 + 2) * NRr + r] = a2;
    RX[(size_t)(b0 + 3) * NRr + r] = a3;
  }
}

// ---------------------------------------------------------------------------
// fused_mid: TWO rows/block, 256 blocks x 512 threads, coalesced weights
// ---------------------------------------------------------------------------
__global__ __launch_bounds__(512) void fused_mid_kernel(
    const float* __restrict__ ent_emb, const int* __restrict__ pred_id,
    const float* __restrict__ X2, const float* __restrict__ S_T,
    const float* __restrict__ cvec, const float* __restrict__ Q_T,
    const float* __restrict__ REatt, const float* __restrict__ relT,
    const float* __restrict__ WaT, const float* __restrict__ v1c,
    float* __restrict__ out_ratt) {
  int b0 = blockIdx.x * 2;
  int t = threadIdx.x;
  int w = t >> 6, lane = t & 63;
  __shared__ float pes[2][200];
  __shared__ float x2s[2][400];
  __shared__ float pp[2][400];
  __shared__ float av[2][200];
  __shared__ float attp[2][2][200];
  __shared__ float wred[2][4];
  if (t < 400)
    pes[t / 200][t % 200] = ent_emb[(size_t)pred_id[b0 + t / 200] * ENTd + t % 200];
  for (int i = t; i < 800; i += 512) x2s[i / 400][i % 400] = X2[(size_t)b0 * 400 + i];
  __syncthreads();
  // la: thread r = t, coalesced S_T[k][r]
  if (t < 400) {
    float c = cvec[t];
    float a0 = c, a1 = c;
    const float* sp = S_T + t;
    for (int k = 0; k < 200; k += 4) {
      float w0 = sp[k * 400], w1 = sp[(k + 1) * 400], w2 = sp[(k + 2) * 400],
            w3 = sp[(k + 3) * 400];
      a0 += w0 * pes[0][k] + w1 * pes[0][k + 1] + w2 * pes[0][k + 2] + w3 * pes[0][k + 3];
      a1 += w0 * pes[1][k] + w1 * pes[1][k + 1] + w2 * pes[1][k + 2] + w3 * pes[1][k + 3];
    }
    pp[0][t] = a0;
    pp[1][t] = a1;
  }
  __syncthreads();
  int row = w >> 2, q = w & 3;  // 4 waves per batch row
  {
    float m = -INFINITY;
    for (int r = q * 64 + lane; r < 400; r += 256) m = fmaxf(m, pp[row][r]);
    m = wave_rmax(m);
    if (lane == 0) wred[row][q] = m;
    __syncthreads();
    float gm = fmaxf(fmaxf(wred[row][0], wred[row][1]),
                     fmaxf(wred[row][2], wred[row][3]));
    __syncthreads();
    float sum = 0.f;
    for (int r = q * 64 + lane; r < 400; r += 256) {
      float e = expf(pp[row][r] - gm);
      pp[row][r] = e;
      sum += e;
    }
    sum = wave_rsum(sum);
    if (lane == 0) wred[row][q] = sum;
    __syncthreads();
    float inv = 1.f / (wred[row][0] + wred[row][1] + wred[row][2] + wred[row][3]);
    for (int r = q * 64 + lane; r < 400; r += 256) pp[row][r] *= inv;
  }
  __syncthreads();
  // attv: j = t%200, h = t/200 (k-split halves), all coalesced
  if (t < 400) {
    int j = t % 200, h = t / 200;
    float b0a, b1a;
    if (h == 0) {
      float v = v1c[j];
      b0a = v; b1a = v;
    } else {
      b0a = 0.f; b1a = 0.f;
    }
    {
      const float* wp = WaT + (size_t)(h * 200) * 200 + j;
      int kb = h * 200;
      for (int k = 0; k < 200; k += 4) {
        float w0 = wp[k * 200], w1 = wp[(k + 1) * 200], w2 = wp[(k + 2) * 200],
              w3 = wp[(k + 3) * 200];
        b0a += w0 * x2s[0][kb + k] + w1 * x2s[0][kb + k + 1] + w2 * x2s[0][kb + k + 2] + w3 * x2s[0][kb + k + 3];
        b1a += w0 * x2s[1][kb + k] + w1 * x2s[1][kb + k + 1] + w2 * x2s[1][kb + k + 2] + w3 * x2s[1][kb + k + 3];
      }
    }
    {
      const float* qp = Q_T + (size_t)(h * 100) * 200 + j;
      int kb = h * 100;
      for (int k = 0; k < 100; k += 4) {
        float w0 = qp[k * 200], w1 = qp[(k + 1) * 200], w2 = qp[(k + 2) * 200],
              w3 = qp[(k + 3) * 200];
        b0a += w0 * pes[0][kb + k] + w1 * pes[0][kb + k + 1] + w2 * pes[0][kb + k + 2] + w3 * pes[0][kb + k + 3];
        b1a += w0 * pes[1][kb + k] + w1 * pes[1][kb + k + 1] + w2 * pes[1][kb + k + 2] + w3 * pes[1][kb + k + 3];
      }
    }
    {
      const float* rp = REatt + (size_t)(h * 200) * 200 + j;
      int rb = h * 200;
      for (int r = 0; r < 200; r += 4) {
        float w0 = rp[r * 200], w1 = rp[(r + 1) * 200], w2 = rp[(r + 2) * 200],
              w3 = rp[(r + 3) * 200];
        b0a += w0 * pp[0][rb + r] + w1 * pp[0][rb + r + 1] + w2 * pp[0][rb + r + 2] + w3 * pp[0][rb + r + 3];
        b1a += w0 * pp[1][rb + r] + w1 * pp[1][rb + r + 1] + w2 * pp[1][rb + r + 2] + w3 * pp[1][rb + r + 3];
      }
    }
    attp[h][0][j] = b0a;
    attp[h][1][j] = b1a;
  }
  __syncthreads();
  if (t < 400) {
    int j = t % 200, s2 = t / 200;
    av[s2][j] = attp[0][s2][j] + attp[1][s2][j];
  }
  __syncthreads();
  // logits: thread r = t, coalesced relT[k][r]
  if (t < 400) {
    const float* rp = relT + t;
    float l0 = 0.f, l1 = 0.f;
    for (int k = 0; k < 200; k += 4) {
      float w0 = rp[k * 400], w1 = rp[(k + 1) * 400], w2 = rp[(k + 2) * 400],
            w3 = rp[(k + 3) * 400];
      l0 += w0 * av[0][k] + w1 * av[0][k + 1] + w2 * av[0][k + 2] + w3 * av[0][k + 3];
      l1 += w0 * av[1][k] + w1 * av[1][k + 1] + w2 * av[1][k + 2] + w3 * av[1][k + 3];
    }
    pp[0][t] = l0;
    pp[1][t] = l1;
  }
  __syncthreads();
  {
    float m = -INFINITY;
    for (int r = q * 64 + lane; r < 400; r += 256) m = fmaxf(m, pp[row][r]);
    m = wave_rmax(m);
    if (lane == 0) wred[row][q] = m;
    __syncthreads();
    float gm = fmaxf(fmaxf(wred[row][0], wred[row][1]),
                     fmaxf(wred[row][2], wred[row][3]));
    __syncthreads();
    float sum = 0.f;
    for (int r = q * 64 + lane; r < 400; r += 256) {
      float e = expf(pp[row][r] - gm);
      pp[row][r] = e;
      sum += e;
    }
    sum = wave_rsum(sum);
    if (lane == 0) wred[row][q] = sum;
    __syncthreads();
    float inv = 1.f / (wred[row][0] + wred[row][1] + wred[row][2] + wred[row][3]);
    for (int r = q * 64 + lane; r < 400; r += 256)
      out_ratt[(size_t)(b0 + row) * 400 + r] = pp[row][r] * inv;
  }
}

// ---------------------------------------------------------------------------
// scores: block per b; ent gather wave-per-action, 4 actions in flight;
// rel part via precomputed RX (wave-uniform scalar lookups).
// ---------------------------------------------------------------------------
__global__ __launch_bounds__(512) void scores_kernel(
    const float* __restrict__ X2, const float* __restrict__ RX,
    const float* __restrict__ ent_emb, const int* __restrict__ r_space,
    const int* __restrict__ e_space, const float* __restrict__ mask,
    float* __restrict__ out_dist, float* __restrict__ out_ent) {
  int b = blockIdx.x;
  int t = threadIdx.x;
  int w = t >> 6, lane = t & 63;
  __shared__ float x2hi[200];
  __shared__ float scl[256];
  __shared__ float wr[8];
  if (t >= 200 && t < 400) x2hi[t - 200] = X2[(size_t)b * ADIMd + t];
  __syncthreads();
  const float4* xh = (const float4*)x2hi;
  // each wave: 32 actions, 4 at a time (4 gathers in flight)
  for (int i0 = 0; i0 < 32; i0 += 4) {
    int abase = w * 32 + i0;
    int e0 = e_space[(size_t)b * AA + abase + 0];
    int e1 = e_space[(size_t)b * AA + abase + 1];
    int e2 = e_space[(size_t)b * AA + abase + 2];
    int e3 = e_space[(size_t)b * AA + abase + 3];
    float p0 = 0.f, p1 = 0.f, p2 = 0.f, p3 = 0.f;
    if (lane < 50) {
      float4 xv = xh[lane];
      float4 v0 = ((const float4*)(ent_emb + (size_t)e0 * ENTd))[lane];
      float4 v1 = ((const float4*)(ent_emb + (size_t)e1 * ENTd))[lane];
      float4 v2 = ((const float4*)(ent_emb + (size_t)e2 * ENTd))[lane];
      float4 v3 = ((const float4*)(ent_emb + (size_t)e3 * ENTd))[lane];
      p0 = dot4(v0, xv);
      p1 = dot4(v1, xv);
      p2 = dot4(v2, xv);
      p3 = dot4(v3, xv);
    }
#pragma unroll
    for (int off = 32; off > 0; off >>= 1) {
      p0 += __shfl_xor(p0, off);
      p1 += __shfl_xor(p1, off);
      p2 += __shfl_xor(p2, off);
      p3 += __shfl_xor(p3, off);
    }
    if (lane == 0) {
      scl[abase + 0] = p0;
      scl[abase + 1] = p1;
      scl[abase + 2] = p2;
      scl[abase + 3] = p3;
    }
  }
  __syncthreads();
  // add RX + mask (per-thread; RX row is 1600B, L2-hit)
  float sc = -INFINITY;
  if (t < 256) {
    int r = r_space[(size_t)b * AA + t];
    sc = scl[t] + RX[(size_t)b * NRr + r] -
         (1.f - mask[(size_t)b * AA + t]) * 1e31f;
  }
  __syncthreads();
  if (w < 4) {
    float m = wave_rmax(sc);
    if (lane == 0) wr[w] = m;
  }
  __syncthreads();
  float gm = fmaxf(fmaxf(wr[0], wr[1]), fmaxf(wr[2], wr[3]));
  float e = (t < 256) ? expf(sc - gm) : 0.f;
  __syncthreads();
  if (w < 4) {
    float s2 = wave_rsum(e);
    if (lane == 0) wr[w] = s2;
  }
  __syncthreads();
  float gs = wr[0] + wr[1] + wr[2] + wr[3];
  float p = e / gs;
  if (t < 256) out_dist[(size_t)b * AA + t] = p;
  float ent = (t < 256) ? -p * logf(p + 1e-20f) : 0.f;
  __syncthreads();
  if (w < 4) {
    float s3 = wave_rsum(ent);
    if (lane == 0) wr[w] = s3;
  }
  __syncthreads();
  if (t == 0) out_ent[b] = wr[0] + wr[1] + wr[2] + wr[3];
}

// ---------------------------------------------------------------------------
extern "C" void kernel_launch(void* const* d_in, const int* in_sizes, int n_in,
                              void* d_out, int out_size, void* d_ws,
                              size_t ws_size, hipStream_t stream) {
  const float* H = (const float*)d_in[0];
  const float* mask = (const float*)d_in[1];
  const float* ent_emb = (const float*)d_in[2];
  const float* rel_emb = (const float*)d_in[3];
  const float* W1 = (const float*)d_in[4];
  const float* b1 = (const float*)d_in[5];
  const float* W2 = (const float*)d_in[6];
  const float* b2 = (const float*)d_in[7];
  const float* W3 = (const float*)d_in[8];
  const float* b3 = (const float*)d_in[9];
  const float* W4 = (const float*)d_in[10];
  const float* b4 = (const float*)d_in[11];
  const float* W5 = (const float*)d_in[12];
  const float* b5 = (const float*)d_in[13];
  const float* W6 = (const float*)d_in[14];
  const float* b6 = (const float*)d_in[15];
  const float* Watt = (const float*)d_in[16];
  const float* batt = (const float*)d_in[17];
  const int* e_idx = (const int*)d_in[18];
  const int* q_idx = (const int*)d_in[19];
  const int* pred_id = (const int*)d_in[20];
  const int* r_space = (const int*)d_in[21];
  const int* e_space = (const int*)d_in[22];

  float* ws = (float*)d_ws;
  float* RK = ws;                   // 80000
  float* S_T = ws + 80000;          // 80000  [200][400]
  float* cvec = ws + 160000;        // 512
  float* P = ws + 160512;           // 40000
  float* Q_T = ws + 200512;         // 40000  [100? no: [200][200]]
  float* W6bb = ws + 240512;        // 40000
  float* REatt = ws + 280512;       // 80000  [400][200]
  float* relT = ws + 360512;        // 80000  [200][400]
  float* WaT = ws + 440512;         // 80000  [400][200]
  float* W1T = ws + 520512;         // 320000 [800][400]
  float* W2T = ws + 840512;         // 160000 [400][400]
  float* ab = ws + 1000512;         // 256
  float* v1 = ws + 1000768;         // 256
  float* X = ws + 1001024;          // 204800
  float* X2 = ws + 1205824;         // 204800
  float* RX = ws + 1410624;         // 204800 [512][400]  (end ~1.62M floats)

  float* out = (float*)d_out;
  float* out_dist = out;                 // [512,256]
  float* out_ent = out + BB * AA;        // [512]
  float* out_ratt = out + BB * AA + BB;  // [512,400]

  hipLaunchKernelGGL(prep1_kernel, dim3(297), dim3(256), 0, stream, rel_emb,
                     W4, b4, W5, b5, W6, Watt, W1, W2, RK, P, W6bb, ab, relT,
                     WaT, W1T, W2T);
  hipLaunchKernelGGL(prep2_kernel, dim3(126), dim3(256), 0, stream, rel_emb,
                     W3, b3, W6, Watt, batt, b6, RK, P, W6bb, ab, S_T, cvec,
                     Q_T, REatt, v1);
  hipLaunchKernelGGL(x1_kernel, dim3(128), dim3(512), 0, stream, ent_emb,
                     rel_emb, H, e_idx, q_idx, W1T, b1, X);
  hipLaunchKernelGGL(x2rx_kernel, dim3(128), dim3(512), 0, stream, X, W2T, b2,
                     relT, X2, RX);
  hipLaunchKernelGGL(fused_mid_kernel, dim3(256), dim3(512), 0, stream,
                     ent_emb, pred_id, X2, S_T, cvec, Q_T, REatt, relT, WaT,
                     v1, out_ratt);
  hipLaunchKernelGGL(scores_kernel, dim3(512), dim3(512), 0, stream, X2, RX,
                     ent_emb, r_space, e_space, mask, out_dist, out_ent);
}